// Round 13
// baseline (169.540 us; speedup 1.0000x reference)
//
#include <hip/hip_runtime.h>

#define NN 50000
#define NE 800000
#define FIN 512
#define FHID 256
#define FOUT 128
#define MPAD 50048  // 782 * 64

#define TW1_BLOCKS  512     // FIN*FHID/256
#define TW2_BLOCKS  128     // FHID*FOUT/256
#define ZERO_BLOCKS 13      // 13*256 >= NBKT*BSTRIDE

// Two-level bucket sort
#define NBKT   196          // coarse bucket = dst >> 8  (49999>>8 = 195)
#define BCAP   5120         // slots/bucket: mean 4082, sigma~64 -> +16 sigma
#define BSTRIDE 16          // bcur counter stride (ints) -> one 64B line each
#define PA_BLOCKS 392
#define E_CHA    2048       // 392 * 2048 = 802816 >= NE

#define PB_BLOCKS    196    // pass B: one block per bucket
#define GEMM1_BLOCKS 1564   // 782 M-tiles x 2 N-tiles (64x128)
#define GEMM2_BLOCKS 782    // 782 M-tiles x 1 N-tile  (64x128)

using bf16x8 = __attribute__((ext_vector_type(8))) short;
using f32x4  = __attribute__((ext_vector_type(4))) float;
using u16x8  = __attribute__((ext_vector_type(8))) unsigned short;

__device__ __forceinline__ unsigned short f2bf(float f) {
    unsigned int u = __builtin_bit_cast(unsigned int, f);
    unsigned int r = (u + 0x7FFFu + ((u >> 16) & 1u)) >> 16;   // RNE
    return (unsigned short)r;
}
__device__ __forceinline__ float bf2f(unsigned short u) {
    return __builtin_bit_cast(float, (unsigned int)u << 16);
}
__device__ __forceinline__ void gload_lds16(const void* g, void* l) {
    __builtin_amdgcn_global_load_lds(
        (const __attribute__((address_space(1))) void*)g,
        (__attribute__((address_space(3))) void*)l, 16, 0, 0);
}

// ---- prep: zero bcur || transpose W1 || transpose W2 ----

__global__ __launch_bounds__(256) void prep_kernel(
    int* __restrict__ bcur,
    const float* __restrict__ W1, unsigned short* __restrict__ W1T,
    const float* __restrict__ W2, unsigned short* __restrict__ W2T) {
    int b = blockIdx.x, tid = threadIdx.x;
    if (b < TW1_BLOCKS) {
        int t = b * 256 + tid;
        int n = t % FHID, k = t / FHID;
        W1T[(size_t)n * FIN + k] = f2bf(W1[t]);
    } else if (b < TW1_BLOCKS + TW2_BLOCKS) {
        int t = (b - TW1_BLOCKS) * 256 + tid;
        int n = t % FOUT, k = t / FOUT;
        W2T[(size_t)n * FHID + k] = f2bf(W2[t]);
    } else {
        int i = (b - TW1_BLOCKS - TW2_BLOCKS) * 256 + tid;
        if (i < NBKT * BSTRIDE) bcur[i] = 0;
    }
}

// ---- pass A: bin edges into 196 coarse buckets (LDS hist, 1 global atomic per
// (block,bucket) reservation; 8-wide MLP; dst kept in registers) ----

__device__ __forceinline__ void passa_body(int pa,
                                           const int* __restrict__ src,
                                           const int* __restrict__ dst,
                                           const float* __restrict__ w,
                                           int* __restrict__ bcur,
                                           int2* __restrict__ barr) {
    __shared__ int hist[NBKT];
    __shared__ int resv[NBKT];
    int tid = threadIdx.x;
    if (tid < NBKT) hist[tid] = 0;
    __syncthreads();
    int base = pa * E_CHA + tid;
    int  d[8];
    bool m[8];
#pragma unroll
    for (int j = 0; j < 8; ++j) {
        int e = base + j * 256;
        m[j] = e < NE;
        d[j] = m[j] ? dst[e] : 0;
    }
#pragma unroll
    for (int j = 0; j < 8; ++j)
        if (m[j]) atomicAdd(&hist[d[j] >> 8], 1);
    __syncthreads();
    if (tid < NBKT) {
        int h = hist[tid];
        resv[tid] = (h > 0) ? atomicAdd(&bcur[tid * BSTRIDE], h) : 0;
        hist[tid] = 0;  // reuse as rank counter
    }
    __syncthreads();
    int   s[8];
    float wv[8];
#pragma unroll
    for (int j = 0; j < 8; ++j) {
        int e = base + j * 256;
        s[j]  = m[j] ? src[e] : 0;
        wv[j] = m[j] ? w[e] : 0.f;
    }
#pragma unroll
    for (int j = 0; j < 8; ++j) {
        if (m[j]) {
            int bb = d[j] >> 8;
            int r  = atomicAdd(&hist[bb], 1);
            int pos = resv[bb] + r;
            if (pos < BCAP)
                barr[(size_t)bb * BCAP + pos] =
                    make_int2(s[j] | ((d[j] & 255) << 16), __float_as_int(wv[j]));
        }
    }
}

// ---- GEMM1 body: 64x128 tile, BK=64, DOUBLE-BUFFERED 2-stage pipeline.
// A staged from f32 X (issue-early reg load -> bf16 cast -> swizzled ds_write),
// B via issue-early global_load_lds. One vmcnt-drain+barrier per K-step. ----

__device__ __forceinline__ void gemm1_body(const float* __restrict__ X,
                                           const unsigned short* __restrict__ BT,
                                           unsigned short* __restrict__ C,
                                           int bx, int by) {
    __shared__ unsigned short As[2][64 * 64];    // 8 KB x2
    __shared__ unsigned short Bs[2][128 * 64];   // 16 KB x2

    const int tid  = threadIdx.x;
    const int lane = tid & 63;
    const int wid  = tid >> 6;
    const int wm   = wid >> 1;
    const int wn   = wid & 1;
    const int brow = bx * 64;
    const int bcol = by * 128;
    const int r15   = lane & 15;
    const int khalf = (lane >> 4) * 8;

    // fixed A-staging geometry: thread handles (g=0,1) rows arow0/arow1, 16 floats each
    const int arow0 = tid >> 3;
    const int arow1 = (256 + tid) >> 3;
    const int acol  = (tid & 7) * 8;
    const bool aok0 = (brow + arow0) < NN;
    const bool aok1 = (brow + arow1) < NN;
    const float4* ap0 = (const float4*)(X + (size_t)(brow + arow0) * FIN + acol);
    const float4* ap1 = (const float4*)(X + (size_t)(brow + arow1) * FIN + acol);
    const int abyte0 = arow0 * 128 + ((acol * 2) ^ ((arow0 & 7) << 4));
    const int abyte1 = arow1 * 128 + ((acol * 2) ^ ((arow1 & 7) << 4));

    f32x4 acc[2][4] = {};
    float4 a00, a01, a10, a11;

    auto issueB = [&](int k0, int buf) {
#pragma unroll
        for (int c = 0; c < 4; ++c) {
            int b   = wid * 4096 + c * 1024 + lane * 16;
            int row = b >> 7;
            int cby = (b & 127) ^ ((row & 7) << 4);
            const char* gb = (const char*)(BT + (size_t)(bcol + row) * FIN + k0) + cby;
            gload_lds16(gb, (char*)Bs[buf] + wid * 4096 + c * 1024);
        }
    };
    auto loadA = [&](int k0) {
        float4 z = make_float4(0.f, 0.f, 0.f, 0.f);
        a00 = z; a01 = z; a10 = z; a11 = z;
        int q = k0 >> 2;
        if (aok0) { a00 = ap0[q]; a01 = ap0[q + 1]; }
        if (aok1) { a10 = ap1[q]; a11 = ap1[q + 1]; }
    };
    auto writeA = [&](int buf) {
        u16x8 v;
        v[0] = f2bf(a00.x); v[1] = f2bf(a00.y); v[2] = f2bf(a00.z); v[3] = f2bf(a00.w);
        v[4] = f2bf(a01.x); v[5] = f2bf(a01.y); v[6] = f2bf(a01.z); v[7] = f2bf(a01.w);
        *(u16x8*)((char*)As[buf] + abyte0) = v;
        v[0] = f2bf(a10.x); v[1] = f2bf(a10.y); v[2] = f2bf(a10.z); v[3] = f2bf(a10.w);
        v[4] = f2bf(a11.x); v[5] = f2bf(a11.y); v[6] = f2bf(a11.z); v[7] = f2bf(a11.w);
        *(u16x8*)((char*)As[buf] + abyte1) = v;
    };

    // prologue: stage K-step 0 into buffer 0
    issueB(0, 0);
    loadA(0);
    writeA(0);
    __syncthreads();

#pragma unroll
    for (int k = 0; k < 8; ++k) {
        const int cur = k & 1, nxt = cur ^ 1;
        if (k < 7) {              // issue next tile EARLY (hides under this tile's compute)
            issueB((k + 1) * 64, nxt);
            loadA((k + 1) * 64);
        }
        bf16x8 af[2][2], bfr[4][2];
#pragma unroll
        for (int m = 0; m < 2; ++m) {
            int row = wm * 32 + m * 16 + r15;
            int rb  = row * 128;
            int sw  = (row & 7) << 4;
#pragma unroll
            for (int ks = 0; ks < 2; ++ks) {
                int byte = rb + (((ks * 32 + khalf) * 2) ^ sw);
                af[m][ks] = *(const bf16x8*)((const char*)As[cur] + byte);
            }
        }
#pragma unroll
        for (int n = 0; n < 4; ++n) {
            int row = wn * 64 + n * 16 + r15;
            int rb  = row * 128;
            int sw  = (row & 7) << 4;
#pragma unroll
            for (int ks = 0; ks < 2; ++ks) {
                int byte = rb + (((ks * 32 + khalf) * 2) ^ sw);
                bfr[n][ks] = *(const bf16x8*)((const char*)Bs[cur] + byte);
            }
        }
#pragma unroll
        for (int m = 0; m < 2; ++m)
#pragma unroll
            for (int n = 0; n < 4; ++n)
#pragma unroll
                for (int ks = 0; ks < 2; ++ks)
                    acc[m][n] = __builtin_amdgcn_mfma_f32_16x16x32_bf16(
                        af[m][ks], bfr[n][ks], acc[m][n], 0, 0, 0);
        if (k < 7) writeA(nxt);   // regs->LDS for next tile (waits its own vmcnt only)
        __syncthreads();
    }

    const int crow0 = brow + wm * 32;
    const int ccol0 = bcol + wn * 64 + r15;
    const int rsub  = (lane >> 4) * 4;
#pragma unroll
    for (int m = 0; m < 2; ++m) {
#pragma unroll
        for (int r = 0; r < 4; ++r) {
            int grow = crow0 + m * 16 + rsub + r;
            if (grow < NN) {
#pragma unroll
                for (int n = 0; n < 4; ++n)
                    C[(size_t)grow * FHID + ccol0 + n * 16] = f2bf(acc[m][n][r]);
            }
        }
    }
}

// ---- fused: passA (first, critical path to passB) || gemm1 ----

__global__ __launch_bounds__(256) void fused_passa_gemm1_kernel(
    const int* __restrict__ src, const int* __restrict__ dst,
    const float* __restrict__ w, int* __restrict__ bcur, int2* __restrict__ barr,
    const float* __restrict__ X, const unsigned short* __restrict__ BT,
    unsigned short* __restrict__ C) {
    if (blockIdx.x < PA_BLOCKS) {
        passa_body(blockIdx.x, src, dst, w, bcur, barr);
    } else {
        int g = blockIdx.x - PA_BLOCKS;
        gemm1_body(X, BT, C, g >> 1, g & 1);   // adjacent blocks share the X row-slice
    }
}

// ---- pass B with SELF-SCAN: each block computes the 196-bucket exclusive scan,
// then LDS-histograms dst&255, writes off[] slice, places edges into csr. ----

__global__ __launch_bounds__(256) void passb_kernel(const int2* __restrict__ barr,
                                                    const int* __restrict__ bcur,
                                                    int* __restrict__ off,
                                                    int2* __restrict__ csr) {
    __shared__ int sc[256];
    __shared__ int cnt[256];
    __shared__ int pre[256];
    __shared__ int wsum[4];
    int b = blockIdx.x, tid = threadIdx.x, lane = tid & 63, wid = tid >> 6;

    int v = (tid < NBKT) ? min(bcur[tid * BSTRIDE], BCAP) : 0;
    int s = v;
#pragma unroll
    for (int d = 1; d < 64; d <<= 1) {
        int t = __shfl_up(s, d, 64);
        if (lane >= d) s += t;
    }
    if (lane == 63) wsum[wid] = s;
    __syncthreads();
    int wo = 0;
#pragma unroll
    for (int j = 0; j < 4; ++j)
        if (j < wid) wo += wsum[j];
    sc[tid] = wo + s - v;
    if (b == 0 && tid == NBKT - 1) off[NN] = wo + s;   // total
    cnt[tid] = 0;
    __syncthreads();

    int bko_b = sc[b];
    int total = min(bcur[b * BSTRIDE], BCAP);
    const int2* seg = barr + (size_t)b * BCAP;

    for (int k = tid; k < total; k += 256)
        atomicAdd(&cnt[(seg[k].x >> 16) & 255], 1);
    __syncthreads();
    int v2 = cnt[tid];
    int s2 = v2;
#pragma unroll
    for (int d = 1; d < 64; d <<= 1) {
        int t = __shfl_up(s2, d, 64);
        if (lane >= d) s2 += t;
    }
    if (lane == 63) wsum[wid] = s2;
    __syncthreads();
    int wo2 = 0;
#pragma unroll
    for (int j = 0; j < 4; ++j)
        if (j < wid) wo2 += wsum[j];
    int base = bko_b + wo2 + s2 - v2;
    pre[tid] = base;
    int n = b * 256 + tid;
    if (n < NN) off[n] = base;
    cnt[tid] = 0;  // reuse as rank counter
    __syncthreads();
    for (int k = tid; k < total; k += 256) {
        int2 pl = seg[k];
        int dlow = (pl.x >> 16) & 255;
        int r = atomicAdd(&cnt[dlow], 1);
        csr[pre[dlow] + r] = make_int2(pl.x & 0xFFFF, pl.y);
    }
}

// ---- GEMM2: 64x128 tile, BK=64, DOUBLE-BUFFERED 2-stage pipeline (both
// operands via issue-early global_load_lds). ----

__global__ __launch_bounds__(256) void gemm2_kernel(const unsigned short* __restrict__ A,
                                                    const unsigned short* __restrict__ BT,
                                                    unsigned short* __restrict__ C) {
    __shared__ unsigned short As[2][64 * 64];
    __shared__ unsigned short Bs[2][128 * 64];

    const int tid  = threadIdx.x;
    const int lane = tid & 63;
    const int wid  = tid >> 6;
    const int wm   = wid >> 1;
    const int wn   = wid & 1;
    const int brow = blockIdx.x * 64;
    const int r15   = lane & 15;
    const int khalf = (lane >> 4) * 8;

    f32x4 acc[2][4] = {};

    auto stage = [&](int k0, int buf) {
#pragma unroll
        for (int c = 0; c < 4; ++c) {
            int b   = wid * 4096 + c * 1024 + lane * 16;
            int row = b >> 7;
            int cby = (b & 127) ^ ((row & 7) << 4);
            const char* gb = (const char*)(BT + (size_t)row * FHID + k0) + cby;
            gload_lds16(gb, (char*)Bs[buf] + wid * 4096 + c * 1024);
        }
#pragma unroll
        for (int c = 0; c < 2; ++c) {
            int b   = wid * 2048 + c * 1024 + lane * 16;
            int row = b >> 7;
            int cby = (b & 127) ^ ((row & 7) << 4);
            const char* ga = (const char*)(A + (size_t)(brow + row) * FHID + k0) + cby;
            gload_lds16(ga, (char*)As[buf] + wid * 2048 + c * 1024);
        }
    };

    stage(0, 0);
    __syncthreads();

#pragma unroll
    for (int k = 0; k < 4; ++k) {
        const int cur = k & 1, nxt = cur ^ 1;
        if (k < 3) stage((k + 1) * 64, nxt);   // issue-early

        bf16x8 af[2][2], bfr[4][2];
#pragma unroll
        for (int m = 0; m < 2; ++m) {
            int row = wm * 32 + m * 16 + r15;
            int rb  = row * 128;
            int sw  = (row & 7) << 4;
#pragma unroll
            for (int ks = 0; ks < 2; ++ks) {
                int byte = rb + (((ks * 32 + khalf) * 2) ^ sw);
                af[m][ks] = *(const bf16x8*)((const char*)As[cur] + byte);
            }
        }
#pragma unroll
        for (int n = 0; n < 4; ++n) {
            int row = wn * 64 + n * 16 + r15;
            int rb  = row * 128;
            int sw  = (row & 7) << 4;
#pragma unroll
            for (int ks = 0; ks < 2; ++ks) {
                int byte = rb + (((ks * 32 + khalf) * 2) ^ sw);
                bfr[n][ks] = *(const bf16x8*)((const char*)Bs[cur] + byte);
            }
        }
#pragma unroll
        for (int m = 0; m < 2; ++m)
#pragma unroll
            for (int n = 0; n < 4; ++n)
#pragma unroll
                for (int ks = 0; ks < 2; ++ks)
                    acc[m][n] = __builtin_amdgcn_mfma_f32_16x16x32_bf16(
                        af[m][ks], bfr[n][ks], acc[m][n], 0, 0, 0);
        __syncthreads();
    }

    const int crow0 = brow + wm * 32;
    const int ccol0 = wn * 64 + r15;
    const int rsub  = (lane >> 4) * 4;
#pragma unroll
    for (int m = 0; m < 2; ++m) {
#pragma unroll
        for (int r = 0; r < 4; ++r) {
            int grow = crow0 + m * 16 + rsub + r;
            if (grow < NN) {
#pragma unroll
                for (int n = 0; n < 4; ++n)
                    C[(size_t)grow * FOUT + ccol0 + n * 16] = f2bf(acc[m][n][r]);
            }
        }
    }
}

// ---- pull-SpMM layer 1: 2 nodes per wave (32-lane halves), u16x8 lane loads ----

__global__ __launch_bounds__(256) void spmm_pair_kernel(const unsigned short* __restrict__ X,
                                                        const int* __restrict__ off,
                                                        const int2* __restrict__ csr,
                                                        unsigned short* __restrict__ Y) {
    int wave = (int)((blockIdx.x * 256 + threadIdx.x) >> 6);
    int lane = threadIdx.x & 63;
    int half = lane >> 5;
    int hl   = lane & 31;
    int n = wave * 2 + half;
    if (n >= NN) return;
    int e0 = off[n];
    int e1 = off[n + 1];
    const size_t fo = (size_t)hl * 8;

    float acc[8] = {};
    for (int e = e0; e < e1; e += 8) {
        int   ss[8];
        float ww[8];
#pragma unroll
        for (int j = 0; j < 8; ++j) {
            int  ee = e + j;
            bool v  = ee < e1;
            int2 sw = csr[v ? ee : e0];
            ss[j] = sw.x;
            ww[j] = v ? __int_as_float(sw.y) : 0.f;
        }
        u16x8 r[8];
#pragma unroll
        for (int j = 0; j < 8; ++j)
            r[j] = *(const u16x8*)(X + (size_t)ss[j] * FHID + fo);
#pragma unroll
        for (int j = 0; j < 8; ++j)
#pragma unroll
            for (int k = 0; k < 8; ++k)
                acc[k] += ww[j] * bf2f(r[j][k]);
    }
    u16x8 o;
#pragma unroll
    for (int k = 0; k < 8; ++k) o[k] = f2bf(fmaxf(acc[k], 0.f));
    *(u16x8*)(Y + (size_t)n * FHID + fo) = o;
}

// ---- pull-SpMM layer 2: 4 nodes per wave (16-lane quarters), f32 output ----

__global__ __launch_bounds__(256) void spmm_quad_kernel(const unsigned short* __restrict__ X,
                                                        const int* __restrict__ off,
                                                        const int2* __restrict__ csr,
                                                        float* __restrict__ Y) {
    int wave = (int)((blockIdx.x * 256 + threadIdx.x) >> 6);
    int lane = threadIdx.x & 63;
    int q  = lane >> 4;
    int hl = lane & 15;
    int n = wave * 4 + q;
    if (n >= NN) return;
    int e0 = off[n];
    int e1 = off[n + 1];
    const size_t fo = (size_t)hl * 8;

    float acc[8] = {};
    for (int e = e0; e < e1; e += 8) {
        int   ss[8];
        float ww[8];
#pragma unroll
        for (int j = 0; j < 8; ++j) {
            int  ee = e + j;
            bool v  = ee < e1;
            int2 sw = csr[v ? ee : e0];
            ss[j] = sw.x;
            ww[j] = v ? __int_as_float(sw.y) : 0.f;
        }
        u16x8 r[8];
#pragma unroll
        for (int j = 0; j < 8; ++j)
            r[j] = *(const u16x8*)(X + (size_t)ss[j] * FOUT + fo);
#pragma unroll
        for (int j = 0; j < 8; ++j)
#pragma unroll
            for (int k = 0; k < 8; ++k)
                acc[k] += ww[j] * bf2f(r[j][k]);
    }
    float4 o0 = make_float4(acc[0], acc[1], acc[2], acc[3]);
    float4 o1 = make_float4(acc[4], acc[5], acc[6], acc[7]);
    *(float4*)(Y + (size_t)n * FOUT + fo) = o0;
    *(float4*)(Y + (size_t)n * FOUT + fo + 4) = o1;
}

// ---------------- launch ----------------

extern "C" void kernel_launch(void* const* d_in, const int* in_sizes, int n_in,
                              void* d_out, int out_size, void* d_ws, size_t ws_size,
                              hipStream_t stream) {
    const float* features = (const float*)d_in[0];
    const int*   edge_src = (const int*)d_in[1];
    const int*   edge_dst = (const int*)d_in[2];
    const float* edge_w   = (const float*)d_in[3];
    const float* W1       = (const float*)d_in[4];
    const float* W2       = (const float*)d_in[5];
    float* out = (float*)d_out;

    char*  ws  = (char*)d_ws;
    size_t ofs = 0;
    auto carve = [&](size_t bytes) -> void* {
        void* r = ws + ofs;
        ofs = (ofs + bytes + 255) & ~(size_t)255;
        return r;
    };
    int*            off   = (int*)carve((NN + 1) * sizeof(int));
    int*            bcur  = (int*)carve(NBKT * BSTRIDE * sizeof(int));
    int2*           barr  = (int2*)carve((size_t)NBKT * BCAP * sizeof(int2));
    int2*           csr   = (int2*)carve((size_t)NE * sizeof(int2));
    unsigned short* W1T   = (unsigned short*)carve((size_t)FHID * FIN * 2);
    unsigned short* W2T   = (unsigned short*)carve((size_t)FOUT * FHID * 2);
    unsigned short* H0b   = (unsigned short*)carve((size_t)MPAD * FHID * 2);
    unsigned short* Hb    = (unsigned short*)carve((size_t)MPAD * FHID * 2);
    unsigned short* H1b   = H0b;  // H0b dead after spmm1

    // prep: transposes + zero bcur
    prep_kernel<<<TW1_BLOCKS + TW2_BLOCKS + ZERO_BLOCKS, 256, 0, stream>>>(
        bcur, W1, W1T, W2, W2T);

    // passA (bucket bin) || gemm1 (H0 = X @ W1, pipelined, direct f32 A)
    fused_passa_gemm1_kernel<<<PA_BLOCKS + GEMM1_BLOCKS, 256, 0, stream>>>(
        edge_src, edge_dst, edge_w, bcur, barr, features, W1T, H0b);

    // passB with self-scan: off[] + csr placement
    passb_kernel<<<PB_BLOCKS, 256, 0, stream>>>(barr, bcur, off, csr);

    // hidden = relu(A @ H0)  (bf16) — 2 nodes/wave
    spmm_pair_kernel<<<6250, 256, 0, stream>>>(H0b, off, csr, Hb);

    // H1 = hidden @ W2 (pipelined) ; out = A @ H1 — 4 nodes/wave
    gemm2_kernel<<<GEMM2_BLOCKS, 256, 0, stream>>>(Hb, W2T, H1b);
    spmm_quad_kernel<<<3125, 256, 0, stream>>>(H1b, off, csr, out);
}

// Round 14
// 169.514 us; speedup vs baseline: 1.0002x; 1.0002x over previous
//
#include <hip/hip_runtime.h>

#define NN 50000
#define NE 800000
#define FIN 512
#define FHID 256
#define FOUT 128
#define MPAD 50048  // 782 * 64

#define TW1_BLOCKS  512     // FIN*FHID/256
#define TW2_BLOCKS  128     // FHID*FOUT/256

// Two-level bucket sort
#define NBKT   196          // coarse bucket = dst >> 8
#define BCAP   5120         // slots/bucket: mean 4082 + 16 sigma
#define BSTRIDE 16          // bcur counter stride (ints) -> one 64B line each
#define PA_BLOCKS 392
#define E_CHA    2048       // 392 * 2048 = 802816 >= NE

#define PB_BLOCKS 196

using bf16x8 = __attribute__((ext_vector_type(8))) short;
using f32x4  = __attribute__((ext_vector_type(4))) float;
using u16x8  = __attribute__((ext_vector_type(8))) unsigned short;

__device__ __forceinline__ unsigned short f2bf(float f) {
    unsigned int u = __builtin_bit_cast(unsigned int, f);
    unsigned int r = (u + 0x7FFFu + ((u >> 16) & 1u)) >> 16;   // RNE
    return (unsigned short)r;
}
__device__ __forceinline__ float bf2f(unsigned short u) {
    return __builtin_bit_cast(float, (unsigned int)u << 16);
}
__device__ __forceinline__ void gload_lds16(const void* g, void* l) {
    __builtin_amdgcn_global_load_lds(
        (const __attribute__((address_space(1))) void*)g,
        (__attribute__((address_space(3))) void*)l, 16, 0, 0);
}

// ---- kernel1: passA (bucket bin) || transpose W1 || transpose W2 ----
// (bcur is zeroed by hipMemsetAsync before this kernel; all parts independent)

__global__ __launch_bounds__(256) void fused_passa_prep_kernel(
    const int* __restrict__ src, const int* __restrict__ dst,
    const float* __restrict__ w, int* __restrict__ bcur, int2* __restrict__ barr,
    const float* __restrict__ W1, unsigned short* __restrict__ W1T,
    const float* __restrict__ W2, unsigned short* __restrict__ W2T) {
    int b = blockIdx.x, tid = threadIdx.x;
    if (b < PA_BLOCKS) {
        __shared__ int hist[NBKT];
        __shared__ int resv[NBKT];
        if (tid < NBKT) hist[tid] = 0;
        __syncthreads();
        int base = b * E_CHA + tid;
        int  d[8];
        bool m[8];
#pragma unroll
        for (int j = 0; j < 8; ++j) {
            int e = base + j * 256;
            m[j] = e < NE;
            d[j] = m[j] ? dst[e] : 0;
        }
#pragma unroll
        for (int j = 0; j < 8; ++j)
            if (m[j]) atomicAdd(&hist[d[j] >> 8], 1);
        __syncthreads();
        if (tid < NBKT) {
            int h = hist[tid];
            resv[tid] = (h > 0) ? atomicAdd(&bcur[tid * BSTRIDE], h) : 0;
            hist[tid] = 0;  // reuse as rank counter
        }
        __syncthreads();
        int   s[8];
        float wv[8];
#pragma unroll
        for (int j = 0; j < 8; ++j) {
            int e = base + j * 256;
            s[j]  = m[j] ? src[e] : 0;
            wv[j] = m[j] ? w[e] : 0.f;
        }
#pragma unroll
        for (int j = 0; j < 8; ++j) {
            if (m[j]) {
                int bb = d[j] >> 8;
                int r  = atomicAdd(&hist[bb], 1);
                int pos = resv[bb] + r;
                if (pos < BCAP)
                    barr[(size_t)bb * BCAP + pos] =
                        make_int2(s[j] | ((d[j] & 255) << 16), __float_as_int(wv[j]));
            }
        }
    } else if (b < PA_BLOCKS + TW1_BLOCKS) {
        int t = (b - PA_BLOCKS) * 256 + tid;
        int n = t % FHID, k = t / FHID;
        W1T[(size_t)n * FIN + k] = f2bf(W1[t]);
    } else {
        int t = (b - PA_BLOCKS - TW1_BLOCKS) * 256 + tid;
        int n = t % FOUT, k = t / FOUT;
        W2T[(size_t)n * FHID + k] = f2bf(W2[t]);
    }
}

// ---- GEMM1 standalone: 64x256 FULL-N tile, BK=64, 4 waves (each wave owns
// cols wid*64..+63 and stages/consumes its OWN B quarter). Single-buffered;
// A(k+1) f32 loads issued into registers early (covered by compute). ----

__global__ __launch_bounds__(256) void gemm1_kernel(const float* __restrict__ X,
                                                    const unsigned short* __restrict__ BT,
                                                    unsigned short* __restrict__ C) {
    __shared__ unsigned short As[64 * 64];    // 8 KB
    __shared__ unsigned short Bs[256 * 64];   // 32 KB

    const int tid  = threadIdx.x;
    const int lane = tid & 63;
    const int wid  = tid >> 6;
    const int brow = blockIdx.x * 64;
    const int r15   = lane & 15;
    const int khalf = (lane >> 4) * 8;

    // A staging geometry: thread covers 2 rows x 8 floats; OOB rows clamped
    // (garbage feeds only never-stored C rows)
    const int arow0 = tid >> 3;
    const int arow1 = 32 + (tid >> 3);
    const int acol  = (tid & 7) * 8;
    const int g0 = min(brow + arow0, NN - 1);
    const int g1 = min(brow + arow1, NN - 1);
    const float4* ap0 = (const float4*)(X + (size_t)g0 * FIN + acol);
    const float4* ap1 = (const float4*)(X + (size_t)g1 * FIN + acol);
    const int ab0 = arow0 * 128 + ((acol * 2) ^ ((arow0 & 7) << 4));
    const int ab1 = arow1 * 128 + ((acol * 2) ^ ((arow1 & 7) << 4));

    f32x4 acc[4][4] = {};
    float4 a00 = ap0[0], a01 = ap0[1], a10 = ap1[0], a11 = ap1[1];  // A(0)

#pragma unroll
    for (int k = 0; k < 8; ++k) {
        const int k0 = k * 64;
        // stage B quarter (rows wid*64..+63): 8 KB per wave, 8 gload_lds
#pragma unroll
        for (int c = 0; c < 8; ++c) {
            int b   = wid * 8192 + c * 1024 + lane * 16;
            int row = b >> 7;
            int cby = (b & 127) ^ ((row & 7) << 4);
            const char* gb = (const char*)(BT + (size_t)row * FIN + k0) + cby;
            gload_lds16(gb, (char*)Bs + wid * 8192 + c * 1024);
        }
        // write A regs -> swizzled LDS
        {
            u16x8 v;
            v[0] = f2bf(a00.x); v[1] = f2bf(a00.y); v[2] = f2bf(a00.z); v[3] = f2bf(a00.w);
            v[4] = f2bf(a01.x); v[5] = f2bf(a01.y); v[6] = f2bf(a01.z); v[7] = f2bf(a01.w);
            *(u16x8*)((char*)As + ab0) = v;
            v[0] = f2bf(a10.x); v[1] = f2bf(a10.y); v[2] = f2bf(a10.z); v[3] = f2bf(a10.w);
            v[4] = f2bf(a11.x); v[5] = f2bf(a11.y); v[6] = f2bf(a11.z); v[7] = f2bf(a11.w);
            *(u16x8*)((char*)As + ab1) = v;
        }
        __syncthreads();

        // issue-early: A(k+1) f32 HBM loads, covered by this iter's compute+barrier
        if (k < 7) {
            int q = (k0 + 64) >> 2;
            a00 = ap0[q]; a01 = ap0[q + 1]; a10 = ap1[q]; a11 = ap1[q + 1];
        }

        // B fragments (held across m-loop), A fragments per-m to limit VGPR
        bf16x8 bfr[4][2];
#pragma unroll
        for (int n = 0; n < 4; ++n) {
            int row = wid * 64 + n * 16 + r15;
            int rb  = row * 128;
            int sw  = (row & 7) << 4;
#pragma unroll
            for (int ks = 0; ks < 2; ++ks)
                bfr[n][ks] = *(const bf16x8*)((const char*)Bs + rb + (((ks * 32 + khalf) * 2) ^ sw));
        }
#pragma unroll
        for (int m = 0; m < 4; ++m) {
            int row = m * 16 + r15;
            int rb  = row * 128;
            int sw  = (row & 7) << 4;
            bf16x8 af0 = *(const bf16x8*)((const char*)As + rb + (((0 + khalf) * 2) ^ sw));
            bf16x8 af1 = *(const bf16x8*)((const char*)As + rb + (((32 + khalf) * 2) ^ sw));
#pragma unroll
            for (int n = 0; n < 4; ++n) {
                acc[m][n] = __builtin_amdgcn_mfma_f32_16x16x32_bf16(af0, bfr[n][0], acc[m][n], 0, 0, 0);
                acc[m][n] = __builtin_amdgcn_mfma_f32_16x16x32_bf16(af1, bfr[n][1], acc[m][n], 0, 0, 0);
            }
        }
        __syncthreads();
    }

    const int rsub = (lane >> 4) * 4;
#pragma unroll
    for (int m = 0; m < 4; ++m) {
#pragma unroll
        for (int r = 0; r < 4; ++r) {
            int grow = brow + m * 16 + rsub + r;
            if (grow < NN) {
#pragma unroll
                for (int n = 0; n < 4; ++n)
                    C[(size_t)grow * FHID + wid * 64 + n * 16 + r15] = f2bf(acc[m][n][r]);
            }
        }
    }
}

// ---- pass B with SELF-SCAN (unchanged) ----

__global__ __launch_bounds__(256) void passb_kernel(const int2* __restrict__ barr,
                                                    const int* __restrict__ bcur,
                                                    int* __restrict__ off,
                                                    int2* __restrict__ csr) {
    __shared__ int sc[256];
    __shared__ int cnt[256];
    __shared__ int pre[256];
    __shared__ int wsum[4];
    int b = blockIdx.x, tid = threadIdx.x, lane = tid & 63, wid = tid >> 6;

    int v = (tid < NBKT) ? min(bcur[tid * BSTRIDE], BCAP) : 0;
    int s = v;
#pragma unroll
    for (int d = 1; d < 64; d <<= 1) {
        int t = __shfl_up(s, d, 64);
        if (lane >= d) s += t;
    }
    if (lane == 63) wsum[wid] = s;
    __syncthreads();
    int wo = 0;
#pragma unroll
    for (int j = 0; j < 4; ++j)
        if (j < wid) wo += wsum[j];
    sc[tid] = wo + s - v;
    if (b == 0 && tid == NBKT - 1) off[NN] = wo + s;
    cnt[tid] = 0;
    __syncthreads();

    int bko_b = sc[b];
    int total = min(bcur[b * BSTRIDE], BCAP);
    const int2* seg = barr + (size_t)b * BCAP;

    for (int k = tid; k < total; k += 256)
        atomicAdd(&cnt[(seg[k].x >> 16) & 255], 1);
    __syncthreads();
    int v2 = cnt[tid];
    int s2 = v2;
#pragma unroll
    for (int d = 1; d < 64; d <<= 1) {
        int t = __shfl_up(s2, d, 64);
        if (lane >= d) s2 += t;
    }
    if (lane == 63) wsum[wid] = s2;
    __syncthreads();
    int wo2 = 0;
#pragma unroll
    for (int j = 0; j < 4; ++j)
        if (j < wid) wo2 += wsum[j];
    int base = bko_b + wo2 + s2 - v2;
    pre[tid] = base;
    int n = b * 256 + tid;
    if (n < NN) off[n] = base;
    cnt[tid] = 0;
    __syncthreads();
    for (int k = tid; k < total; k += 256) {
        int2 pl = seg[k];
        int dlow = (pl.x >> 16) & 255;
        int r = atomicAdd(&cnt[dlow], 1);
        csr[pre[dlow] + r] = make_int2(pl.x & 0xFFFF, pl.y);
    }
}

// ---- GEMM2: 64x128 FULL-N tile, BK=64, 4 waves (wave owns cols wid*32..+31),
// single-buffered, both operands via gload_lds. ----

__global__ __launch_bounds__(256) void gemm2_kernel(const unsigned short* __restrict__ A,
                                                    const unsigned short* __restrict__ BT,
                                                    unsigned short* __restrict__ C) {
    __shared__ unsigned short As[64 * 64];    // 8 KB
    __shared__ unsigned short Bs[128 * 64];   // 16 KB

    const int tid  = threadIdx.x;
    const int lane = tid & 63;
    const int wid  = tid >> 6;
    const int brow = blockIdx.x * 64;
    const int r15   = lane & 15;
    const int khalf = (lane >> 4) * 8;

    f32x4 acc[4][2] = {};

#pragma unroll
    for (int k = 0; k < 4; ++k) {
        const int k0 = k * 64;
        // B quarter: rows wid*32..+31 (4 KB per wave, 4 gload_lds)
#pragma unroll
        for (int c = 0; c < 4; ++c) {
            int b   = wid * 4096 + c * 1024 + lane * 16;
            int row = b >> 7;
            int cby = (b & 127) ^ ((row & 7) << 4);
            const char* gb = (const char*)(BT + (size_t)row * FHID + k0) + cby;
            gload_lds16(gb, (char*)Bs + wid * 4096 + c * 1024);
        }
        // A: 64 rows (2 KB per wave, 2 gload_lds); rows < MPAD always valid
#pragma unroll
        for (int c = 0; c < 2; ++c) {
            int b   = wid * 2048 + c * 1024 + lane * 16;
            int row = b >> 7;
            int cby = (b & 127) ^ ((row & 7) << 4);
            const char* ga = (const char*)(A + (size_t)(brow + row) * FHID + k0) + cby;
            gload_lds16(ga, (char*)As + wid * 2048 + c * 1024);
        }
        __syncthreads();

        bf16x8 bfr[2][2];
#pragma unroll
        for (int n = 0; n < 2; ++n) {
            int row = wid * 32 + n * 16 + r15;
            int rb  = row * 128;
            int sw  = (row & 7) << 4;
#pragma unroll
            for (int ks = 0; ks < 2; ++ks)
                bfr[n][ks] = *(const bf16x8*)((const char*)Bs + rb + (((ks * 32 + khalf) * 2) ^ sw));
        }
#pragma unroll
        for (int m = 0; m < 4; ++m) {
            int row = m * 16 + r15;
            int rb  = row * 128;
            int sw  = (row & 7) << 4;
            bf16x8 af0 = *(const bf16x8*)((const char*)As + rb + (((0 + khalf) * 2) ^ sw));
            bf16x8 af1 = *(const bf16x8*)((const char*)As + rb + (((32 + khalf) * 2) ^ sw));
#pragma unroll
            for (int n = 0; n < 2; ++n) {
                acc[m][n] = __builtin_amdgcn_mfma_f32_16x16x32_bf16(af0, bfr[n][0], acc[m][n], 0, 0, 0);
                acc[m][n] = __builtin_amdgcn_mfma_f32_16x16x32_bf16(af1, bfr[n][1], acc[m][n], 0, 0, 0);
            }
        }
        __syncthreads();
    }

    const int rsub = (lane >> 4) * 4;
#pragma unroll
    for (int m = 0; m < 4; ++m) {
#pragma unroll
        for (int r = 0; r < 4; ++r) {
            int grow = brow + m * 16 + rsub + r;
            if (grow < NN) {
#pragma unroll
                for (int n = 0; n < 2; ++n)
                    C[(size_t)grow * FOUT + wid * 32 + n * 16 + r15] = f2bf(acc[m][n][r]);
            }
        }
    }
}

// ---- pull-SpMM layer 1: 2 nodes per wave (32-lane halves), u16x8 lane loads ----

__global__ __launch_bounds__(256) void spmm_pair_kernel(const unsigned short* __restrict__ X,
                                                        const int* __restrict__ off,
                                                        const int2* __restrict__ csr,
                                                        unsigned short* __restrict__ Y) {
    int wave = (int)((blockIdx.x * 256 + threadIdx.x) >> 6);
    int lane = threadIdx.x & 63;
    int half = lane >> 5;
    int hl   = lane & 31;
    int n = wave * 2 + half;
    if (n >= NN) return;
    int e0 = off[n];
    int e1 = off[n + 1];
    const size_t fo = (size_t)hl * 8;

    float acc[8] = {};
    for (int e = e0; e < e1; e += 8) {
        int   ss[8];
        float ww[8];
#pragma unroll
        for (int j = 0; j < 8; ++j) {
            int  ee = e + j;
            bool v  = ee < e1;
            int2 sw = csr[v ? ee : e0];
            ss[j] = sw.x;
            ww[j] = v ? __int_as_float(sw.y) : 0.f;
        }
        u16x8 r[8];
#pragma unroll
        for (int j = 0; j < 8; ++j)
            r[j] = *(const u16x8*)(X + (size_t)ss[j] * FHID + fo);
#pragma unroll
        for (int j = 0; j < 8; ++j)
#pragma unroll
            for (int k = 0; k < 8; ++k)
                acc[k] += ww[j] * bf2f(r[j][k]);
    }
    u16x8 o;
#pragma unroll
    for (int k = 0; k < 8; ++k) o[k] = f2bf(fmaxf(acc[k], 0.f));
    *(u16x8*)(Y + (size_t)n * FHID + fo) = o;
}

// ---- pull-SpMM layer 2: 4 nodes per wave (16-lane quarters), f32 output ----

__global__ __launch_bounds__(256) void spmm_quad_kernel(const unsigned short* __restrict__ X,
                                                        const int* __restrict__ off,
                                                        const int2* __restrict__ csr,
                                                        float* __restrict__ Y) {
    int wave = (int)((blockIdx.x * 256 + threadIdx.x) >> 6);
    int lane = threadIdx.x & 63;
    int q  = lane >> 4;
    int hl = lane & 15;
    int n = wave * 4 + q;
    if (n >= NN) return;
    int e0 = off[n];
    int e1 = off[n + 1];
    const size_t fo = (size_t)hl * 8;

    float acc[8] = {};
    for (int e = e0; e < e1; e += 8) {
        int   ss[8];
        float ww[8];
#pragma unroll
        for (int j = 0; j < 8; ++j) {
            int  ee = e + j;
            bool v  = ee < e1;
            int2 sw = csr[v ? ee : e0];
            ss[j] = sw.x;
            ww[j] = v ? __int_as_float(sw.y) : 0.f;
        }
        u16x8 r[8];
#pragma unroll
        for (int j = 0; j < 8; ++j)
            r[j] = *(const u16x8*)(X + (size_t)ss[j] * FOUT + fo);
#pragma unroll
        for (int j = 0; j < 8; ++j)
#pragma unroll
            for (int k = 0; k < 8; ++k)
                acc[k] += ww[j] * bf2f(r[j][k]);
    }
    float4 o0 = make_float4(acc[0], acc[1], acc[2], acc[3]);
    float4 o1 = make_float4(acc[4], acc[5], acc[6], acc[7]);
    *(float4*)(Y + (size_t)n * FOUT + fo) = o0;
    *(float4*)(Y + (size_t)n * FOUT + fo + 4) = o1;
}

// ---------------- launch ----------------

extern "C" void kernel_launch(void* const* d_in, const int* in_sizes, int n_in,
                              void* d_out, int out_size, void* d_ws, size_t ws_size,
                              hipStream_t stream) {
    const float* features = (const float*)d_in[0];
    const int*   edge_src = (const int*)d_in[1];
    const int*   edge_dst = (const int*)d_in[2];
    const float* edge_w   = (const float*)d_in[3];
    const float* W1       = (const float*)d_in[4];
    const float* W2       = (const float*)d_in[5];
    float* out = (float*)d_out;

    char*  ws  = (char*)d_ws;
    size_t ofs = 0;
    auto carve = [&](size_t bytes) -> void* {
        void* r = ws + ofs;
        ofs = (ofs + bytes + 255) & ~(size_t)255;
        return r;
    };
    int*            off   = (int*)carve((NN + 1) * sizeof(int));
    int*            bcur  = (int*)carve(NBKT * BSTRIDE * sizeof(int));
    int2*           barr  = (int2*)carve((size_t)NBKT * BCAP * sizeof(int2));
    int2*           csr   = (int2*)carve((size_t)NE * sizeof(int2));
    unsigned short* W1T   = (unsigned short*)carve((size_t)FHID * FIN * 2);
    unsigned short* W2T   = (unsigned short*)carve((size_t)FOUT * FHID * 2);
    unsigned short* H0b   = (unsigned short*)carve((size_t)MPAD * FHID * 2);
    unsigned short* Hb    = (unsigned short*)carve((size_t)MPAD * FHID * 2);
    unsigned short* H1b   = H0b;  // H0b dead after spmm1

    hipMemsetAsync(bcur, 0, NBKT * BSTRIDE * sizeof(int), stream);

    // passA (bucket bin) || transpose W1 || transpose W2
    fused_passa_prep_kernel<<<PA_BLOCKS + TW1_BLOCKS + TW2_BLOCKS, 256, 0, stream>>>(
        edge_src, edge_dst, edge_w, bcur, barr, W1, W1T, W2, W2T);

    // gemm1 STANDALONE: H0 = X @ W1 (64x256 full-N tiles, direct f32 A)
    gemm1_kernel<<<MPAD / 64, 256, 0, stream>>>(features, W1T, H0b);

    // passB with self-scan: off[] + csr placement
    passb_kernel<<<PB_BLOCKS, 256, 0, stream>>>(barr, bcur, off, csr);

    // hidden = relu(A @ H0)  (bf16) — 2 nodes/wave
    spmm_pair_kernel<<<6250, 256, 0, stream>>>(H0b, off, csr, Hb);

    // H1 = hidden @ W2 (64x128 full-N) ; out = A @ H1 — 4 nodes/wave
    gemm2_kernel<<<MPAD / 64, 256, 0, stream>>>(Hb, W2T, H1b);
    spmm_quad_kernel<<<3125, 256, 0, stream>>>(H1b, off, csr, out);
}